// Round 8
// baseline (32.674 us; speedup 1.0000x reference)
//
#include <hip/hip_runtime.h>
#include <math.h>

#define BB 4
#define MM 1024
#define NN 16384
#define KPB 8
#define TPB 256
#define NSPLIT 4
#define NSEG (NN / NSPLIT)                    // 4096 points per segment
#define GROUPS_PER_B (MM / KPB)               // 128
#define BLOCKS_PER_B (GROUPS_PER_B * NSPLIT)  // 512

typedef unsigned int u32;
typedef unsigned long long u64;

__device__ __forceinline__ u32 ord_f32(float x) {
    u32 f = __float_as_uint(x);
    return f ^ ((u32)((int)f >> 31) | 0x80000000u);   // monotone float->uint map
}

// part[kpid * NSPLIT + seg] = pack(ord(s_min), argmin_n), s = p2 - 2*dot
// (d2 = k2 + s; k2 const per keypoint => same argmin & tie order)
__global__ __launch_bounds__(TPB, 4) void knn_kernel(
    const float* __restrict__ kp, const float* __restrict__ pc,
    u64* __restrict__ part)
{
    const int b   = blockIdx.x / BLOCKS_PER_B;
    const int rem = blockIdx.x % BLOCKS_PER_B;
    const int m0  = (rem / NSPLIT) * KPB;
    const int seg = rem % NSPLIT;
    const int nbase = seg * NSEG;
    const int tid = threadIdx.x;

    const float* kpx = kp + (b*3 + 0)*MM;
    const float* kpy = kp + (b*3 + 1)*MM;
    const float* kpz = kp + (b*3 + 2)*MM;
    const float* pcx = pc + (b*3 + 0)*NN;
    const float* pcy = pc + (b*3 + 1)*NN;
    const float* pcz = pc + (b*3 + 2)*NN;

    float m2x[KPB], m2y[KPB], m2z[KPB];
    #pragma unroll
    for (int k = 0; k < KPB; ++k) {
        m2x[k] = -2.0f * kpx[m0 + k];
        m2y[k] = -2.0f * kpy[m0 + k];
        m2z[k] = -2.0f * kpz[m0 + k];
    }

    float bests[KPB];
    int   besti[KPB];
    #pragma unroll
    for (int k = 0; k < KPB; ++k) { bests[k] = INFINITY; besti[k] = 0; }

    // 4 iterations: each thread 4 consecutive points, stride 1024
    for (int n0 = nbase + tid * 4; n0 < nbase + NSEG; n0 += TPB * 4) {
        float4 x4 = *reinterpret_cast<const float4*>(pcx + n0);
        float4 y4 = *reinterpret_cast<const float4*>(pcy + n0);
        float4 z4 = *reinterpret_cast<const float4*>(pcz + n0);
        float pxs[4] = {x4.x, x4.y, x4.z, x4.w};
        float pys[4] = {y4.x, y4.y, y4.z, y4.w};
        float pzs[4] = {z4.x, z4.y, z4.z, z4.w};
        #pragma unroll
        for (int j = 0; j < 4; ++j) {
            const float px = pxs[j], py = pys[j], pz = pzs[j];
            const float p2 = px*px + py*py + pz*pz;
            const int n = n0 + j;
            #pragma unroll
            for (int k = 0; k < KPB; ++k) {
                const float s = fmaf(m2x[k], px,
                                fmaf(m2y[k], py,
                                fmaf(m2z[k], pz, p2)));        // 3 FMA / pair
                if (s < bests[k]) { bests[k] = s; besti[k] = n; }  // first n wins
            }
        }
    }

    // wave u64 min reduce (min s, tie -> min n)
    u64 wkey[KPB];
    #pragma unroll
    for (int k = 0; k < KPB; ++k) {
        u64 key = ((u64)ord_f32(bests[k]) << 32) | (u32)besti[k];
        #pragma unroll
        for (int off = 32; off > 0; off >>= 1) {
            u64 o = __shfl_down(key, off, 64);
            if (o < key) key = o;
        }
        wkey[k] = key;
    }

    __shared__ u64 skey[TPB/64][KPB];
    const int wave = tid >> 6, lane = tid & 63;
    if (lane == 0) {
        #pragma unroll
        for (int k = 0; k < KPB; ++k) skey[wave][k] = wkey[k];
    }
    __syncthreads();

    if (tid < KPB) {
        u64 key = skey[0][tid];
        #pragma unroll
        for (int w = 1; w < TPB/64; ++w) {
            u64 o = skey[w][tid];
            if (o < key) key = o;
        }
        part[(b*MM + m0 + tid) * NSPLIT + seg] = key;   // plain store
    }
}

// Single block, 1024 threads: merge partials, gather, loss, reduce, plain-store out[0].
#define LTPB 1024
__global__ __launch_bounds__(LTPB) void loss_kernel(
    const float* __restrict__ kp, const float* __restrict__ pc,
    const float* __restrict__ sn, const u64* __restrict__ part,
    float* __restrict__ out)
{
    const int tid = threadIdx.x;
    float acc = 0.0f;

    #pragma unroll
    for (int r = 0; r < (BB*MM)/LTPB; ++r) {            // 4 keypoints per thread
        const int kpid = r * LTPB + tid;
        const int b = kpid / MM, m = kpid % MM;

        ulonglong4 p4 = *reinterpret_cast<const ulonglong4*>(part + kpid * NSPLIT);
        u64 key = p4.x;
        if (p4.y < key) key = p4.y;
        if (p4.z < key) key = p4.z;
        if (p4.w < key) key = p4.w;
        const int idx = (int)(key & 0xFFFFFFFFull);

        const float kx = kp[(b*3+0)*MM + m];
        const float ky = kp[(b*3+1)*MM + m];
        const float kz = kp[(b*3+2)*MM + m];
        const float px = pc[(b*3+0)*NN + idx];
        const float py = pc[(b*3+1)*NN + idx];
        const float pz = pc[(b*3+2)*NN + idx];
        const float sx = sn[(b*3+0)*NN + idx];
        const float sy = sn[(b*3+1)*NN + idx];
        const float sz = sn[(b*3+2)*NN + idx];

        const float dx = kx - px, dy = ky - py, dz = kz - pz;
        const float dn = sqrtf(dx*dx + dy*dy + dz*dz);
        const float inv = 1.0f / (dn + 1e-7f);
        const float dot = (sx*dx + sy*dy + sz*dz) * inv;
        acc += dot * dot;
    }

    acc *= (1.0f / (float)(BB * MM));

    #pragma unroll
    for (int off = 32; off > 0; off >>= 1)
        acc += __shfl_down(acc, off, 64);

    __shared__ float wsum[LTPB / 64];
    const int wave = tid >> 6, lane = tid & 63;
    if (lane == 0) wsum[wave] = acc;
    __syncthreads();
    if (tid == 0) {
        float s = 0.0f;
        #pragma unroll
        for (int w = 0; w < LTPB / 64; ++w) s += wsum[w];
        out[0] = s;                                      // plain store, every call
    }
}

extern "C" void kernel_launch(void* const* d_in, const int* in_sizes, int n_in,
                              void* d_out, int out_size, void* d_ws, size_t ws_size,
                              hipStream_t stream) {
    const float* kp = (const float*)d_in[0];
    const float* pc = (const float*)d_in[1];
    const float* sn = (const float*)d_in[2];
    float* out = (float*)d_out;
    u64* part = (u64*)d_ws;                              // 4096*4*8 = 128 KB

    knn_kernel<<<BB * BLOCKS_PER_B, TPB, 0, stream>>>(kp, pc, part);
    loss_kernel<<<1, LTPB, 0, stream>>>(kp, pc, sn, part, out);
}

// Round 9
// 21.003 us; speedup vs baseline: 1.5557x; 1.5557x over previous
//
#include <hip/hip_runtime.h>
#include <math.h>

#define BB 4
#define MM 1024
#define NN 16384
#define KPB 8
#define TPB 256
#define NSPLIT 4
#define NSEG (NN / NSPLIT)                    // 4096 points per segment
#define GROUPS_PER_B (MM / KPB)               // 128
#define BLOCKS_PER_B (GROUPS_PER_B * NSPLIT)  // 512

typedef unsigned int u32;
typedef unsigned long long u64;

__device__ __forceinline__ u32 ord_f32(float x) {
    u32 f = __float_as_uint(x);
    return f ^ ((u32)((int)f >> 31) | 0x80000000u);   // monotone float->uint map
}

// part[kpid * NSPLIT + seg] = pack(ord(s_min), argmin_n), s = p2 - 2*dot
// (d2 = k2 + s; k2 const per keypoint => same argmin & tie order)
// Also zeroes out[0] (block 0) so no memset node is needed.
__global__ __launch_bounds__(TPB, 4) void knn_kernel(
    const float* __restrict__ kp, const float* __restrict__ pc,
    u64* __restrict__ part, float* __restrict__ out)
{
    if (blockIdx.x == 0 && threadIdx.x == 0) out[0] = 0.0f;  // ordered before loss kernel

    const int b   = blockIdx.x / BLOCKS_PER_B;
    const int rem = blockIdx.x % BLOCKS_PER_B;
    const int m0  = (rem / NSPLIT) * KPB;
    const int seg = rem % NSPLIT;
    const int nbase = seg * NSEG;
    const int tid = threadIdx.x;

    const float* kpx = kp + (b*3 + 0)*MM;
    const float* kpy = kp + (b*3 + 1)*MM;
    const float* kpz = kp + (b*3 + 2)*MM;
    const float* pcx = pc + (b*3 + 0)*NN;
    const float* pcy = pc + (b*3 + 1)*NN;
    const float* pcz = pc + (b*3 + 2)*NN;

    float m2x[KPB], m2y[KPB], m2z[KPB];
    #pragma unroll
    for (int k = 0; k < KPB; ++k) {
        m2x[k] = -2.0f * kpx[m0 + k];
        m2y[k] = -2.0f * kpy[m0 + k];
        m2z[k] = -2.0f * kpz[m0 + k];
    }

    float bests[KPB];
    int   besti[KPB];
    #pragma unroll
    for (int k = 0; k < KPB; ++k) { bests[k] = INFINITY; besti[k] = 0; }

    // 4 iterations: each thread 4 consecutive points, stride 1024
    for (int n0 = nbase + tid * 4; n0 < nbase + NSEG; n0 += TPB * 4) {
        float4 x4 = *reinterpret_cast<const float4*>(pcx + n0);
        float4 y4 = *reinterpret_cast<const float4*>(pcy + n0);
        float4 z4 = *reinterpret_cast<const float4*>(pcz + n0);
        float pxs[4] = {x4.x, x4.y, x4.z, x4.w};
        float pys[4] = {y4.x, y4.y, y4.z, y4.w};
        float pzs[4] = {z4.x, z4.y, z4.z, z4.w};
        #pragma unroll
        for (int j = 0; j < 4; ++j) {
            const float px = pxs[j], py = pys[j], pz = pzs[j];
            const float p2 = px*px + py*py + pz*pz;
            const int n = n0 + j;
            #pragma unroll
            for (int k = 0; k < KPB; ++k) {
                const float s = fmaf(m2x[k], px,
                                fmaf(m2y[k], py,
                                fmaf(m2z[k], pz, p2)));        // 3 FMA / pair
                if (s < bests[k]) { bests[k] = s; besti[k] = n; }  // first n wins
            }
        }
    }

    // wave u64 min reduce (min s, tie -> min n)
    u64 wkey[KPB];
    #pragma unroll
    for (int k = 0; k < KPB; ++k) {
        u64 key = ((u64)ord_f32(bests[k]) << 32) | (u32)besti[k];
        #pragma unroll
        for (int off = 32; off > 0; off >>= 1) {
            u64 o = __shfl_down(key, off, 64);
            if (o < key) key = o;
        }
        wkey[k] = key;
    }

    __shared__ u64 skey[TPB/64][KPB];
    const int wave = tid >> 6, lane = tid & 63;
    if (lane == 0) {
        #pragma unroll
        for (int k = 0; k < KPB; ++k) skey[wave][k] = wkey[k];
    }
    __syncthreads();

    if (tid < KPB) {
        u64 key = skey[0][tid];
        #pragma unroll
        for (int w = 1; w < TPB/64; ++w) {
            u64 o = skey[w][tid];
            if (o < key) key = o;
        }
        part[(b*MM + m0 + tid) * NSPLIT + seg] = key;   // plain store
    }
}

// 16 blocks x 256 threads: one keypoint per thread.
__global__ __launch_bounds__(TPB) void loss_kernel(
    const float* __restrict__ kp, const float* __restrict__ pc,
    const float* __restrict__ sn, const u64* __restrict__ part,
    float* __restrict__ out)
{
    const int kpid = blockIdx.x * TPB + threadIdx.x;   // 0..4095
    const int b = kpid / MM, m = kpid % MM;

    ulonglong4 p4 = *reinterpret_cast<const ulonglong4*>(part + kpid * NSPLIT);
    u64 key = p4.x;
    if (p4.y < key) key = p4.y;
    if (p4.z < key) key = p4.z;
    if (p4.w < key) key = p4.w;
    const int idx = (int)(key & 0xFFFFFFFFull);

    const float kx = kp[(b*3+0)*MM + m];
    const float ky = kp[(b*3+1)*MM + m];
    const float kz = kp[(b*3+2)*MM + m];
    const float px = pc[(b*3+0)*NN + idx];
    const float py = pc[(b*3+1)*NN + idx];
    const float pz = pc[(b*3+2)*NN + idx];
    const float sx = sn[(b*3+0)*NN + idx];
    const float sy = sn[(b*3+1)*NN + idx];
    const float sz = sn[(b*3+2)*NN + idx];

    const float dx = kx - px, dy = ky - py, dz = kz - pz;
    const float dn = sqrtf(dx*dx + dy*dy + dz*dz);
    const float inv = 1.0f / (dn + 1e-7f);
    const float dot = (sx*dx + sy*dy + sz*dz) * inv;
    float loss = dot * dot * (1.0f / (float)(BB * MM));

    #pragma unroll
    for (int off = 32; off > 0; off >>= 1)
        loss += __shfl_down(loss, off, 64);

    __shared__ float wsum[TPB / 64];
    const int wave = threadIdx.x >> 6, lane = threadIdx.x & 63;
    if (lane == 0) wsum[wave] = loss;
    __syncthreads();
    if (threadIdx.x == 0) {
        float s = 0.0f;
        #pragma unroll
        for (int w = 0; w < TPB / 64; ++w) s += wsum[w];
        atomicAdd(out, s);
    }
}

extern "C" void kernel_launch(void* const* d_in, const int* in_sizes, int n_in,
                              void* d_out, int out_size, void* d_ws, size_t ws_size,
                              hipStream_t stream) {
    const float* kp = (const float*)d_in[0];
    const float* pc = (const float*)d_in[1];
    const float* sn = (const float*)d_in[2];
    float* out = (float*)d_out;
    u64* part = (u64*)d_ws;                              // 4096*4*8 = 128 KB

    knn_kernel<<<BB * BLOCKS_PER_B, TPB, 0, stream>>>(kp, pc, part, out);
    loss_kernel<<<(BB * MM) / TPB, TPB, 0, stream>>>(kp, pc, sn, part, out);
}